// Round 9
// baseline (49.888 us; speedup 1.0000x reference)
//
#include <hip/hip_runtime.h>
#include <hip/hip_bf16.h>

#define SVOX 13824   // 24*24*24
#define CIN 128
#define NHEAD 4
#define HDIM 32

// attention brick geometry
#define BD 2
#define BH 4
#define BW 8
#define WD (BD+2)
#define WH (BH+2)
#define WW (BW+2)
#define NWIN (WD*WH*WW)   // 240

typedef __attribute__((ext_vector_type(8))) short short8;
typedef __attribute__((ext_vector_type(4))) float f32x4;
#if defined(__has_builtin)
#if __has_builtin(__builtin_amdgcn_fdot2_f32_bf16)
#define HAVE_DOT2BF 1
typedef __attribute__((ext_vector_type(2))) __bf16 bf16x2;
#endif
#if __has_builtin(__builtin_amdgcn_mov_dpp)
#define HAVE_DPP 1
#endif
#endif

__device__ __forceinline__ unsigned short f2bf(float x) {
    unsigned u = __float_as_uint(x);
    u += 0x7FFFu + ((u >> 16) & 1u);
    return (unsigned short)(u >> 16);
}
__device__ __forceinline__ float dot2bf(unsigned a, unsigned b, float c) {
#ifdef HAVE_DOT2BF
    return __builtin_amdgcn_fdot2_f32_bf16(__builtin_bit_cast(bf16x2, a),
                                           __builtin_bit_cast(bf16x2, b), c, false);
#else
    return __uint_as_float(a << 16) * __uint_as_float(b << 16)
         + __uint_as_float(a & 0xffff0000u) * __uint_as_float(b & 0xffff0000u) + c;
#endif
}
template<int CTRL>
__device__ __forceinline__ float quad_dpp(float x) {
#ifdef HAVE_DPP
    return __int_as_float(__builtin_amdgcn_mov_dpp(__float_as_int(x), CTRL, 0xf, 0xf, true));
#else
    return __shfl_xor(x, (CTRL == 0xB1) ? 1 : 2);
#endif
}

// ---------------------------------------------------------------------------
// Kernel 0: prep — convert qkv_w/proj_w to bf16, pack pos pairs. ~262 KB.
// ---------------------------------------------------------------------------
__global__ __launch_bounds__(256) void prep_kernel(
    const float* __restrict__ qkv_w,
    const float* __restrict__ proj_w,
    const float* __restrict__ pos,
    ushort* __restrict__ Wq,
    ushort* __restrict__ Wp,
    unsigned* __restrict__ pe)
{
    int id = blockIdx.x * 256 + threadIdx.x;
    if (id < 6144) {                     // qkv_w: 49152 f32 / 8
        float4 a = *(const float4*)(qkv_w + (size_t)id * 8);
        float4 b = *(const float4*)(qkv_w + (size_t)id * 8 + 4);
        ushort4 u, v;
        u.x = f2bf(a.x); u.y = f2bf(a.y); u.z = f2bf(a.z); u.w = f2bf(a.w);
        v.x = f2bf(b.x); v.y = f2bf(b.y); v.z = f2bf(b.z); v.w = f2bf(b.w);
        *(ushort4*)(Wq + (size_t)id * 8) = u;
        *(ushort4*)(Wq + (size_t)id * 8 + 4) = v;
    } else if (id < 8192) {              // proj_w: 16384 f32 / 8
        int j = id - 6144;
        float4 a = *(const float4*)(proj_w + (size_t)j * 8);
        float4 b = *(const float4*)(proj_w + (size_t)j * 8 + 4);
        ushort4 u, v;
        u.x = f2bf(a.x); u.y = f2bf(a.y); u.z = f2bf(a.z); u.w = f2bf(a.w);
        v.x = f2bf(b.x); v.y = f2bf(b.y); v.z = f2bf(b.z); v.w = f2bf(b.w);
        *(ushort4*)(Wp + (size_t)j * 8) = u;
        *(ushort4*)(Wp + (size_t)j * 8 + 4) = v;
    } else if (id < 8192 + 432) {        // pos pairs: [27 win][16 cpair]
        int j = id - 8192;
        int w = j >> 4, cp = j & 15;
        unsigned lo = f2bf(pos[(2 * cp) * 27 + w]);
        unsigned hi = f2bf(pos[(2 * cp + 1) * 27 + w]);
        pe[j] = lo | (hi << 16);
    }
}

// ---------------------------------------------------------------------------
// Kernel 1: QKV GEMM. Tile 192(o) x 64(s), K=128 (X in 2 chunks of 64).
// W pre-converted bf16, staged full-K once per block. 4 waves; wave frag map:
// o = mf*64 + wid*16 (mf<3), s = nf*16 (nf<4) -> 48 MFMA/wave.
// 3-pass epilogue (p = mf): clean 64-channel slab per pass.
// ---------------------------------------------------------------------------
__global__ __launch_bounds__(256) void qkv_gemm(
    const float* __restrict__ X,
    const ushort* __restrict__ Wg,
    const float* __restrict__ bias,
    ushort* __restrict__ q_out,
    ushort* __restrict__ k_out,
    ushort* __restrict__ v_out)
{
    __shared__ __align__(16) unsigned char smem[61440];
    ushort* Wb = (ushort*)smem;                 // [192][136] bf16
    ushort* Xs = (ushort*)(smem + 52224);       // [64 s][72 k] bf16
    float*  T  = (float*)smem;                  // epilogue alias [64][68]

    const int t    = threadIdx.x;
    const int s0   = blockIdx.x * 64;
    const int o0   = blockIdx.y * 192;
    const int b    = blockIdx.z;
    const int lane = t & 63;
    const int wid  = t >> 6;
    const int l15  = lane & 15;
    const int g4   = lane >> 4;

    // stage W [192][128] bf16 (straight copy, stride 136)
    #pragma unroll
    for (int i = 0; i < 12; i++) {
        int f = t + i * 256;
        int row = f >> 4, c8 = f & 15;
        *(uint4*)(Wb + row * 136 + c8 * 8) =
            *(const uint4*)(Wg + (size_t)(o0 + row) * CIN + c8 * 8);
    }

    f32x4 acc[3][4];
    #pragma unroll
    for (int mf = 0; mf < 3; mf++)
        #pragma unroll
        for (int nf = 0; nf < 4; nf++)
            acc[mf][nf] = (f32x4){0.f, 0.f, 0.f, 0.f};

    const int sx = t & 63;
    const int kg = t >> 6;

    for (int chunk = 0; chunk < 2; chunk++) {
        __syncthreads();
        ushort xk[16];
        #pragma unroll
        for (int i = 0; i < 16; i++) {
            int k = kg * 16 + i;
            xk[i] = f2bf(X[((size_t)b * CIN + chunk * 64 + k) * SVOX + s0 + sx]);
        }
        #pragma unroll
        for (int j = 0; j < 2; j++) {
            short8 v;
            #pragma unroll
            for (int e = 0; e < 8; e++) v[e] = (short)xk[j * 8 + e];
            *(short8*)(Xs + sx * 72 + kg * 16 + j * 8) = v;
        }
        __syncthreads();

        #pragma unroll
        for (int ks = 0; ks < 2; ks++) {
            short8 Bf[4], Af[3];
            #pragma unroll
            for (int nf = 0; nf < 4; nf++)
                Bf[nf] = *(const short8*)(Xs + (nf * 16 + l15) * 72 + ks * 32 + g4 * 8);
            #pragma unroll
            for (int mf = 0; mf < 3; mf++)
                Af[mf] = *(const short8*)(Wb + (mf * 64 + wid * 16 + l15) * 136 + chunk * 64 + ks * 32 + g4 * 8);
            #pragma unroll
            for (int mf = 0; mf < 3; mf++)
                #pragma unroll
                for (int nf = 0; nf < 4; nf++)
                    acc[mf][nf] = __builtin_amdgcn_mfma_f32_16x16x32_bf16(Af[mf], Bf[nf], acc[mf][nf], 0, 0, 0);
        }
    }

    // 3-pass epilogue; pass p handles o in [o0+p*64, o0+p*64+64)
    #pragma unroll
    for (int p = 0; p < 3; p++) {
        __syncthreads();
        #pragma unroll
        for (int nf = 0; nf < 4; nf++)
            *(f32x4*)(T + (nf * 16 + l15) * 68 + wid * 16 + g4 * 4) = acc[p][nf];
        __syncthreads();
        #pragma unroll
        for (int i = 0; i < 4; i++) {
            int f = t + i * 256;
            int og = f & 15, sl = f >> 4;
            float4 v = *(float4*)(T + sl * 68 + og * 4);
            int o_g = o0 + p * 64 + og * 4;
            v.x += bias[o_g]; v.y += bias[o_g + 1]; v.z += bias[o_g + 2]; v.w += bias[o_g + 3];
            int part = o_g >> 7, pc = o_g & 127;
            int head = pc >> 5, ic = pc & 31;
            size_t base = (((size_t)b * NHEAD + head) * SVOX + s0 + sl) * HDIM + ic;
            ushort4 u;
            u.x = f2bf(v.x); u.y = f2bf(v.y); u.z = f2bf(v.z); u.w = f2bf(v.w);
            ushort* dst = (part == 0) ? q_out : (part == 1) ? k_out : v_out;
            *(ushort4*)(dst + base) = u;
        }
    }
}

// ---------------------------------------------------------------------------
// Kernel 2: brick-LDS windowed attention (unchanged from R8).
// ---------------------------------------------------------------------------
__global__ __launch_bounds__(256, 5) void attn_kernel(
    const ushort* __restrict__ qbf,
    const ushort* __restrict__ kbf,
    const ushort* __restrict__ vbf,
    const unsigned* __restrict__ pe_g,
    ushort* __restrict__ aout)
{
    __shared__ __align__(16) ushort Kl[NWIN * 32];       // 15360 B
    __shared__ __align__(16) ushort Vl[NWIN * 32];       // 15360 B

    const int t = threadIdx.x;
    const int br = blockIdx.x;           // 216 bricks: 12(d) x 6(h) x 3(w)
    const int n  = blockIdx.y;
    const int b  = blockIdx.z;
    const int bw_ = br % 3;
    const int bh_ = (br / 3) % 6;
    const int bd_ = br / 18;
    const int d0 = bd_ * BD, h0 = bh_ * BH, w0 = bw_ * BW;

    const ushort* kb = kbf + ((size_t)b * NHEAD + n) * (size_t)SVOX * HDIM;
    const ushort* vb = vbf + ((size_t)b * NHEAD + n) * (size_t)SVOX * HDIM;

    #pragma unroll
    for (int i = 0; i < 4; i++) {
        int f = t + i * 256;
        if (f < NWIN * 4) {
            int u = f >> 2, ch = f & 3;
            int ud = u / (WH * WW);
            int r  = u - ud * (WH * WW);
            int uh = r / WW;
            int uw = r - uh * WW;
            int gd = d0 + ud - 1, gh = h0 + uh - 1, gw = w0 + uw - 1;
            bool valid = ((unsigned)gd < 24u) & ((unsigned)gh < 24u) & ((unsigned)gw < 24u);
            size_t gsv = valid ? (size_t)(gd * 576 + gh * 24 + gw) : 0;
            uint4 kv = *(const uint4*)(kb + gsv * HDIM + ch * 8);
            uint4 vv = *(const uint4*)(vb + gsv * HDIM + ch * 8);
            if (!valid) { kv = make_uint4(0,0,0,0); vv = make_uint4(0,0,0,0); }
            *(uint4*)(Kl + u * 32 + ch * 8) = kv;
            *(uint4*)(Vl + u * 32 + ch * 8) = vv;
        }
    }

    const int p   = t >> 2;          // local voxel 0..63
    const int sub = t & 3;           // 8-channel group
    const int pw = p & 7, ph = (p >> 3) & 3, pd = p >> 5;
    const int dd0 = d0 + pd, hh0 = h0 + ph, ww0 = w0 + pw;
    const int sv = dd0 * 576 + hh0 * 24 + ww0;
    uint4 qpk = *(const uint4*)(qbf + (((size_t)b * NHEAD + n) * SVOX + sv) * HDIM + sub * 8);

    // q . pos partials from global pe table (L1 broadcast), overlaps staging
    float sc[27];
    #pragma unroll
    for (int s = 0; s < 27; s++) {
        uint4 pp = *(const uint4*)(pe_g + s * 16 + sub * 4);
        float a = dot2bf(qpk.x, pp.x, 0.f);
        a = dot2bf(qpk.y, pp.y, a);
        a = dot2bf(qpk.z, pp.z, a);
        a = dot2bf(qpk.w, pp.w, a);
        sc[s] = a;
    }

    __syncthreads();

    const int wc = (pd + 1) * (WH * WW) + (ph + 1) * WW + (pw + 1);
    const ushort* Kbase = Kl + wc * 32 + sub * 8;

    #pragma unroll
    for (int s = 0; s < 27; s++) {
        const int di = s / 9 - 1, dj = (s / 3) % 3 - 1, dl = s % 3 - 1;
        const int off = (di * (WH * WW) + dj * WW + dl) * 32;
        uint4 kk = *(const uint4*)(Kbase + off);
        float a = sc[s];
        a = dot2bf(qpk.x, kk.x, a);
        a = dot2bf(qpk.y, kk.y, a);
        a = dot2bf(qpk.z, kk.z, a);
        a = dot2bf(qpk.w, kk.w, a);
        sc[s] = a;
    }

    #pragma unroll
    for (int s = 0; s < 27; s++) {
        sc[s] += quad_dpp<0xB1>(sc[s]);   // xor 1
        sc[s] += quad_dpp<0x4E>(sc[s]);   // xor 2
    }

    const float scale = 0.17677669529663687f;
    float mx = -1e30f;
    #pragma unroll
    for (int s = 0; s < 27; s++) {
        sc[s] *= scale;
        mx = fmaxf(mx, sc[s]);
    }
    float sum = 0.f;
    #pragma unroll
    for (int s = 0; s < 27; s++) {
        float e = __expf(sc[s] - mx);
        sc[s] = e;
        sum += e;
    }
    float inv = 1.f / sum;

    const ushort* Vbase = Vl + wc * 32 + sub * 8;
    float o[8];
    #pragma unroll
    for (int i = 0; i < 8; i++) o[i] = 0.f;
    #pragma unroll
    for (int s = 0; s < 27; s++) {
        const int di = s / 9 - 1, dj = (s / 3) % 3 - 1, dl = s % 3 - 1;
        const int off = (di * (WH * WW) + dj * WW + dl) * 32;
        uint4 vv = *(const uint4*)(Vbase + off);
        float pr = sc[s];
        o[0] += pr * __uint_as_float(vv.x << 16);
        o[1] += pr * __uint_as_float(vv.x & 0xffff0000u);
        o[2] += pr * __uint_as_float(vv.y << 16);
        o[3] += pr * __uint_as_float(vv.y & 0xffff0000u);
        o[4] += pr * __uint_as_float(vv.z << 16);
        o[5] += pr * __uint_as_float(vv.z & 0xffff0000u);
        o[6] += pr * __uint_as_float(vv.w << 16);
        o[7] += pr * __uint_as_float(vv.w & 0xffff0000u);
    }

    uint4 ou;
    ou.x = (unsigned)f2bf(o[0] * inv) | ((unsigned)f2bf(o[1] * inv) << 16);
    ou.y = (unsigned)f2bf(o[2] * inv) | ((unsigned)f2bf(o[3] * inv) << 16);
    ou.z = (unsigned)f2bf(o[4] * inv) | ((unsigned)f2bf(o[5] * inv) << 16);
    ou.w = (unsigned)f2bf(o[6] * inv) | ((unsigned)f2bf(o[7] * inv) << 16);
    *(uint4*)(aout + ((size_t)b * SVOX + sv) * CIN + n * HDIM + sub * 8) = ou;
}

// ---------------------------------------------------------------------------
// Kernel 3: proj GEMM, tile 64(o) x 128(s), K=128 single shot, bf16 W preconv.
// Wave frag map: o = (wid&1)*32 + mf*16 (mf<2), s = (wid>>1)*64 + nf*16 (nf<4)
// -> 32 MFMA/wave.
// ---------------------------------------------------------------------------
__global__ __launch_bounds__(256) void proj_gemm(
    const ushort* __restrict__ Xa,
    const ushort* __restrict__ Wg,
    const float* __restrict__ bias,
    float* __restrict__ out)
{
    __shared__ __align__(16) unsigned char smem[52224];
    ushort* Wb = (ushort*)smem;                 // [64][136] bf16
    ushort* Xs = (ushort*)(smem + 17408);       // [128 s][136 k] bf16
    float*  T  = (float*)smem;                  // epilogue alias [64][132]

    const int t    = threadIdx.x;
    const int s0   = blockIdx.x * 128;
    const int o0   = blockIdx.y * 64;
    const int b    = blockIdx.z;
    const int lane = t & 63;
    const int wid  = t >> 6;
    const int l15  = lane & 15;
    const int g4   = lane >> 4;
    const int wo   = (wid & 1) * 32;
    const int ws   = (wid >> 1) * 64;

    // stage W [64][128] bf16 (straight copy)
    #pragma unroll
    for (int i = 0; i < 4; i++) {
        int f = t + i * 256;
        int row = f >> 4, c8 = f & 15;
        *(uint4*)(Wb + row * 136 + c8 * 8) =
            *(const uint4*)(Wg + (size_t)(o0 + row) * CIN + c8 * 8);
    }
    // stage X [128 s][128 c] bf16 (straight copy)
    #pragma unroll
    for (int i = 0; i < 8; i++) {
        int f = t + i * 256;
        int row = f >> 4, c8 = f & 15;
        *(uint4*)(Xs + row * 136 + c8 * 8) =
            *(const uint4*)(Xa + ((size_t)b * SVOX + s0 + row) * CIN + c8 * 8);
    }
    __syncthreads();

    f32x4 acc[2][4];
    #pragma unroll
    for (int mf = 0; mf < 2; mf++)
        #pragma unroll
        for (int nf = 0; nf < 4; nf++)
            acc[mf][nf] = (f32x4){0.f, 0.f, 0.f, 0.f};

    #pragma unroll
    for (int ks = 0; ks < 4; ks++) {
        short8 Af[2], Bf[4];
        #pragma unroll
        for (int mf = 0; mf < 2; mf++)
            Af[mf] = *(const short8*)(Wb + (wo + mf * 16 + l15) * 136 + ks * 32 + g4 * 8);
        #pragma unroll
        for (int nf = 0; nf < 4; nf++)
            Bf[nf] = *(const short8*)(Xs + (ws + nf * 16 + l15) * 136 + ks * 32 + g4 * 8);
        #pragma unroll
        for (int mf = 0; mf < 2; mf++)
            #pragma unroll
            for (int nf = 0; nf < 4; nf++)
                acc[mf][nf] = __builtin_amdgcn_mfma_f32_16x16x32_bf16(Af[mf], Bf[nf], acc[mf][nf], 0, 0, 0);
    }

    __syncthreads();
    // epilogue: [o][s] transpose -> coalesced f32 store to [B][128][S]
    #pragma unroll
    for (int mf = 0; mf < 2; mf++)
        #pragma unroll
        for (int nf = 0; nf < 4; nf++) {
            int s  = ws + nf * 16 + l15;
            int mb = wo + mf * 16 + g4 * 4;
            #pragma unroll
            for (int r = 0; r < 4; r++)
                T[(mb + r) * 132 + s] = acc[mf][nf][r];
        }
    __syncthreads();
    #pragma unroll
    for (int i = 0; i < 8; i++) {
        int f = t + i * 256;
        int s4 = f & 31, m = f >> 5;
        float4 v = *(float4*)(T + m * 132 + s4 * 4);
        float bi = bias[o0 + m];
        v.x += bi; v.y += bi; v.z += bi; v.w += bi;
        *(float4*)(out + ((size_t)b * CIN + o0 + m) * SVOX + s0 + s4 * 4) = v;
    }
}

extern "C" void kernel_launch(void* const* d_in, const int* in_sizes, int n_in,
                              void* d_out, int out_size, void* d_ws, size_t ws_size,
                              hipStream_t stream) {
    const float* x      = (const float*)d_in[0];
    const float* qkv_w  = (const float*)d_in[1];
    const float* qkv_b  = (const float*)d_in[2];
    const float* proj_w = (const float*)d_in[3];
    const float* proj_b = (const float*)d_in[4];
    const float* pos    = (const float*)d_in[5];
    float* out = (float*)d_out;

    const size_t HSZ = (size_t)2 * NHEAD * SVOX * HDIM;   // elems per q/k/v tensor
    ushort* qb  = (ushort*)d_ws;                          // bf16 [2][4][S][32]
    ushort* kbp = qb + HSZ;
    ushort* vbp = kbp + HSZ;
    ushort* attn_o = vbp + HSZ;                           // bf16 [2][S][128]
    ushort* Wq  = attn_o + HSZ;                           // bf16 [384][128]
    ushort* Wp  = Wq + 384 * CIN;                         // bf16 [128][128]
    unsigned* pe_p = (unsigned*)(Wp + CIN * CIN);         // [27][16] packed pairs

    prep_kernel<<<34, 256, 0, stream>>>(qkv_w, proj_w, pos, Wq, Wp, pe_p);
    qkv_gemm<<<dim3(SVOX/64, 2, 2), 256, 0, stream>>>(x, Wq, qkv_b, qb, kbp, vbp);
    attn_kernel<<<dim3(216, NHEAD, 2), 256, 0, stream>>>(qb, kbp, vbp, pe_p, attn_o);
    proj_gemm<<<dim3(SVOX/128, 2, 2), 256, 0, stream>>>(attn_o, Wp, proj_b, out);
}

// Round 10
// 49.266 us; speedup vs baseline: 1.0126x; 1.0126x over previous
//
#include <hip/hip_runtime.h>
#include <hip/hip_bf16.h>

#define SVOX 13824   // 24*24*24
#define CIN 128
#define NHEAD 4
#define HDIM 32

// attention brick geometry
#define BD 2
#define BH 4
#define BW 8
#define WD (BD+2)
#define WH (BH+2)
#define WW (BW+2)
#define NWIN (WD*WH*WW)   // 240

typedef __attribute__((ext_vector_type(8))) short short8;
typedef __attribute__((ext_vector_type(4))) float f32x4;
#if defined(__has_builtin)
#if __has_builtin(__builtin_amdgcn_fdot2_f32_bf16)
#define HAVE_DOT2BF 1
typedef __attribute__((ext_vector_type(2))) __bf16 bf16x2;
#endif
#if __has_builtin(__builtin_amdgcn_mov_dpp)
#define HAVE_DPP 1
#endif
#endif

__device__ __forceinline__ unsigned short f2bf(float x) {
    unsigned u = __float_as_uint(x);
    u += 0x7FFFu + ((u >> 16) & 1u);
    return (unsigned short)(u >> 16);
}
__device__ __forceinline__ float dot2bf(unsigned a, unsigned b, float c) {
#ifdef HAVE_DOT2BF
    return __builtin_amdgcn_fdot2_f32_bf16(__builtin_bit_cast(bf16x2, a),
                                           __builtin_bit_cast(bf16x2, b), c, false);
#else
    return __uint_as_float(a << 16) * __uint_as_float(b << 16)
         + __uint_as_float(a & 0xffff0000u) * __uint_as_float(b & 0xffff0000u) + c;
#endif
}
template<int CTRL>
__device__ __forceinline__ float quad_dpp(float x) {
#ifdef HAVE_DPP
    return __int_as_float(__builtin_amdgcn_mov_dpp(__float_as_int(x), CTRL, 0xf, 0xf, true));
#else
    return __shfl_xor(x, (CTRL == 0xB1) ? 1 : 2);
#endif
}

// ---------------------------------------------------------------------------
// Kernel 0: prep — convert qkv_w/proj_w to bf16, pack pos pairs.
// ---------------------------------------------------------------------------
__global__ __launch_bounds__(256) void prep_kernel(
    const float* __restrict__ qkv_w,
    const float* __restrict__ proj_w,
    const float* __restrict__ pos,
    ushort* __restrict__ Wq,
    ushort* __restrict__ Wp,
    unsigned* __restrict__ pe)
{
    int id = blockIdx.x * 256 + threadIdx.x;
    if (id < 6144) {                     // qkv_w: 49152 f32 / 8
        float4 a = *(const float4*)(qkv_w + (size_t)id * 8);
        float4 b = *(const float4*)(qkv_w + (size_t)id * 8 + 4);
        ushort4 u, v;
        u.x = f2bf(a.x); u.y = f2bf(a.y); u.z = f2bf(a.z); u.w = f2bf(a.w);
        v.x = f2bf(b.x); v.y = f2bf(b.y); v.z = f2bf(b.z); v.w = f2bf(b.w);
        *(ushort4*)(Wq + (size_t)id * 8) = u;
        *(ushort4*)(Wq + (size_t)id * 8 + 4) = v;
    } else if (id < 8192) {              // proj_w: 16384 f32 / 8
        int j = id - 6144;
        float4 a = *(const float4*)(proj_w + (size_t)j * 8);
        float4 b = *(const float4*)(proj_w + (size_t)j * 8 + 4);
        ushort4 u, v;
        u.x = f2bf(a.x); u.y = f2bf(a.y); u.z = f2bf(a.z); u.w = f2bf(a.w);
        v.x = f2bf(b.x); v.y = f2bf(b.y); v.z = f2bf(b.z); v.w = f2bf(b.w);
        *(ushort4*)(Wp + (size_t)j * 8) = u;
        *(ushort4*)(Wp + (size_t)j * 8 + 4) = v;
    } else if (id < 8192 + 432) {        // pos pairs: [27 win][16 cpair]
        int j = id - 8192;
        int w = j >> 4, cp = j & 15;
        unsigned lo = f2bf(pos[(2 * cp) * 27 + w]);
        unsigned hi = f2bf(pos[(2 * cp + 1) * 27 + w]);
        pe[j] = lo | (hi << 16);
    }
}

// ---------------------------------------------------------------------------
// Kernel 1: QKV GEMM, 64(o) x 64(s) tile, K=128 in 2 chunks, 4 waves 32x32.
// XCD-aware remap: linear bid -> (xcd = bid&7); each XCD owns 27 contiguous
// s-tiles x 6 o-blocks -> per-XCD input working set ~1 MB, L2-resident:
// X and W fetched from L3/HBM exactly once.
// ---------------------------------------------------------------------------
__global__ __launch_bounds__(256) void qkv_gemm(
    const float* __restrict__ X,
    const ushort* __restrict__ Wg,
    const float* __restrict__ bias,
    ushort* __restrict__ q_out,
    ushort* __restrict__ k_out,
    ushort* __restrict__ v_out)
{
    __shared__ __align__(16) unsigned char smem[26624];
    ushort* Wb = (ushort*)smem;                 // [64][136] bf16
    ushort* Xs = (ushort*)(smem + 17408);       // [64 s][72 k] bf16
    float*  T  = (float*)smem;                  // epilogue alias [64][68]

    const int t    = threadIdx.x;
    // XCD-aware remap: 1296 blocks = 8 XCDs x 162 (27 s-tiles x 6 o-blocks)
    const int bid  = blockIdx.x;
    const int xcd  = bid & 7;
    const int wk   = xcd * 162 + (bid >> 3);
    const int s0   = (wk / 6) * 64;
    const int o0   = (wk % 6) * 64;
    const int b    = blockIdx.z;
    const int lane = t & 63;
    const int wid  = t >> 6;
    const int l15  = lane & 15;
    const int g4   = lane >> 4;
    const int wm   = (wid >> 1) * 32;
    const int wn   = (wid & 1) * 32;

    // stage W [64][128] bf16 (straight copy)
    #pragma unroll
    for (int i = 0; i < 4; i++) {
        int f = t + i * 256;
        int row = f >> 4, c8 = f & 15;
        *(uint4*)(Wb + row * 136 + c8 * 8) =
            *(const uint4*)(Wg + (size_t)(o0 + row) * CIN + c8 * 8);
    }

    f32x4 acc[2][2];
    #pragma unroll
    for (int mf = 0; mf < 2; mf++)
        #pragma unroll
        for (int nf = 0; nf < 2; nf++)
            acc[mf][nf] = (f32x4){0.f, 0.f, 0.f, 0.f};

    const int sx = t & 63;
    const int kg = t >> 6;

    for (int chunk = 0; chunk < 2; chunk++) {
        __syncthreads();
        ushort xk[16];
        #pragma unroll
        for (int i = 0; i < 16; i++) {
            int k = kg * 16 + i;
            xk[i] = f2bf(X[((size_t)b * CIN + chunk * 64 + k) * SVOX + s0 + sx]);
        }
        #pragma unroll
        for (int j = 0; j < 2; j++) {
            short8 v;
            #pragma unroll
            for (int e = 0; e < 8; e++) v[e] = (short)xk[j * 8 + e];
            *(short8*)(Xs + sx * 72 + kg * 16 + j * 8) = v;
        }
        __syncthreads();

        #pragma unroll
        for (int ks = 0; ks < 2; ks++) {
            short8 Af[2], Bf[2];
            #pragma unroll
            for (int mf = 0; mf < 2; mf++)
                Af[mf] = *(const short8*)(Wb + (wm + mf * 16 + l15) * 136 + chunk * 64 + ks * 32 + g4 * 8);
            #pragma unroll
            for (int nf = 0; nf < 2; nf++)
                Bf[nf] = *(const short8*)(Xs + (wn + nf * 16 + l15) * 72 + ks * 32 + g4 * 8);
            #pragma unroll
            for (int mf = 0; mf < 2; mf++)
                #pragma unroll
                for (int nf = 0; nf < 2; nf++)
                    acc[mf][nf] = __builtin_amdgcn_mfma_f32_16x16x32_bf16(Af[mf], Bf[nf], acc[mf][nf], 0, 0, 0);
        }
    }

    __syncthreads();
    // epilogue: transpose via LDS, pack bf16, scatter to q/k/v [B][4][S][32]
    #pragma unroll
    for (int mf = 0; mf < 2; mf++)
        #pragma unroll
        for (int nf = 0; nf < 2; nf++) {
            int s  = wn + nf * 16 + l15;
            int mb = wm + mf * 16 + g4 * 4;
            *(f32x4*)(T + s * 68 + mb) = acc[mf][nf];
        }
    __syncthreads();
    #pragma unroll
    for (int i = 0; i < 4; i++) {
        int f = t + i * 256;
        int og = f & 15, sl = f >> 4;
        float4 v = *(float4*)(T + sl * 68 + og * 4);
        int o_g = o0 + og * 4;
        v.x += bias[o_g]; v.y += bias[o_g + 1]; v.z += bias[o_g + 2]; v.w += bias[o_g + 3];
        int part = o_g >> 7, pc = o_g & 127;
        int head = pc >> 5, ic = pc & 31;
        size_t base = (((size_t)b * NHEAD + head) * SVOX + s0 + sl) * HDIM + ic;
        ushort4 u;
        u.x = f2bf(v.x); u.y = f2bf(v.y); u.z = f2bf(v.z); u.w = f2bf(v.w);
        ushort* dst = (part == 0) ? q_out : (part == 1) ? k_out : v_out;
        *(ushort4*)(dst + base) = u;
    }
}

// ---------------------------------------------------------------------------
// Kernel 2: brick-LDS windowed attention (unchanged from R8).
// ---------------------------------------------------------------------------
__global__ __launch_bounds__(256, 5) void attn_kernel(
    const ushort* __restrict__ qbf,
    const ushort* __restrict__ kbf,
    const ushort* __restrict__ vbf,
    const unsigned* __restrict__ pe_g,
    ushort* __restrict__ aout)
{
    __shared__ __align__(16) ushort Kl[NWIN * 32];       // 15360 B
    __shared__ __align__(16) ushort Vl[NWIN * 32];       // 15360 B

    const int t = threadIdx.x;
    const int br = blockIdx.x;           // 216 bricks: 12(d) x 6(h) x 3(w)
    const int n  = blockIdx.y;
    const int b  = blockIdx.z;
    const int bw_ = br % 3;
    const int bh_ = (br / 3) % 6;
    const int bd_ = br / 18;
    const int d0 = bd_ * BD, h0 = bh_ * BH, w0 = bw_ * BW;

    const ushort* kb = kbf + ((size_t)b * NHEAD + n) * (size_t)SVOX * HDIM;
    const ushort* vb = vbf + ((size_t)b * NHEAD + n) * (size_t)SVOX * HDIM;

    #pragma unroll
    for (int i = 0; i < 4; i++) {
        int f = t + i * 256;
        if (f < NWIN * 4) {
            int u = f >> 2, ch = f & 3;
            int ud = u / (WH * WW);
            int r  = u - ud * (WH * WW);
            int uh = r / WW;
            int uw = r - uh * WW;
            int gd = d0 + ud - 1, gh = h0 + uh - 1, gw = w0 + uw - 1;
            bool valid = ((unsigned)gd < 24u) & ((unsigned)gh < 24u) & ((unsigned)gw < 24u);
            size_t gsv = valid ? (size_t)(gd * 576 + gh * 24 + gw) : 0;
            uint4 kv = *(const uint4*)(kb + gsv * HDIM + ch * 8);
            uint4 vv = *(const uint4*)(vb + gsv * HDIM + ch * 8);
            if (!valid) { kv = make_uint4(0,0,0,0); vv = make_uint4(0,0,0,0); }
            *(uint4*)(Kl + u * 32 + ch * 8) = kv;
            *(uint4*)(Vl + u * 32 + ch * 8) = vv;
        }
    }

    const int p   = t >> 2;          // local voxel 0..63
    const int sub = t & 3;           // 8-channel group
    const int pw = p & 7, ph = (p >> 3) & 3, pd = p >> 5;
    const int dd0 = d0 + pd, hh0 = h0 + ph, ww0 = w0 + pw;
    const int sv = dd0 * 576 + hh0 * 24 + ww0;
    uint4 qpk = *(const uint4*)(qbf + (((size_t)b * NHEAD + n) * SVOX + sv) * HDIM + sub * 8);

    // q . pos partials from global pe table (L1 broadcast), overlaps staging
    float sc[27];
    #pragma unroll
    for (int s = 0; s < 27; s++) {
        uint4 pp = *(const uint4*)(pe_g + s * 16 + sub * 4);
        float a = dot2bf(qpk.x, pp.x, 0.f);
        a = dot2bf(qpk.y, pp.y, a);
        a = dot2bf(qpk.z, pp.z, a);
        a = dot2bf(qpk.w, pp.w, a);
        sc[s] = a;
    }

    __syncthreads();

    const int wc = (pd + 1) * (WH * WW) + (ph + 1) * WW + (pw + 1);
    const ushort* Kbase = Kl + wc * 32 + sub * 8;

    #pragma unroll
    for (int s = 0; s < 27; s++) {
        const int di = s / 9 - 1, dj = (s / 3) % 3 - 1, dl = s % 3 - 1;
        const int off = (di * (WH * WW) + dj * WW + dl) * 32;
        uint4 kk = *(const uint4*)(Kbase + off);
        float a = sc[s];
        a = dot2bf(qpk.x, kk.x, a);
        a = dot2bf(qpk.y, kk.y, a);
        a = dot2bf(qpk.z, kk.z, a);
        a = dot2bf(qpk.w, kk.w, a);
        sc[s] = a;
    }

    #pragma unroll
    for (int s = 0; s < 27; s++) {
        sc[s] += quad_dpp<0xB1>(sc[s]);   // xor 1
        sc[s] += quad_dpp<0x4E>(sc[s]);   // xor 2
    }

    const float scale = 0.17677669529663687f;
    float mx = -1e30f;
    #pragma unroll
    for (int s = 0; s < 27; s++) {
        sc[s] *= scale;
        mx = fmaxf(mx, sc[s]);
    }
    float sum = 0.f;
    #pragma unroll
    for (int s = 0; s < 27; s++) {
        float e = __expf(sc[s] - mx);
        sc[s] = e;
        sum += e;
    }
    float inv = 1.f / sum;

    const ushort* Vbase = Vl + wc * 32 + sub * 8;
    float o[8];
    #pragma unroll
    for (int i = 0; i < 8; i++) o[i] = 0.f;
    #pragma unroll
    for (int s = 0; s < 27; s++) {
        const int di = s / 9 - 1, dj = (s / 3) % 3 - 1, dl = s % 3 - 1;
        const int off = (di * (WH * WW) + dj * WW + dl) * 32;
        uint4 vv = *(const uint4*)(Vbase + off);
        float pr = sc[s];
        o[0] += pr * __uint_as_float(vv.x << 16);
        o[1] += pr * __uint_as_float(vv.x & 0xffff0000u);
        o[2] += pr * __uint_as_float(vv.y << 16);
        o[3] += pr * __uint_as_float(vv.y & 0xffff0000u);
        o[4] += pr * __uint_as_float(vv.z << 16);
        o[5] += pr * __uint_as_float(vv.z & 0xffff0000u);
        o[6] += pr * __uint_as_float(vv.w << 16);
        o[7] += pr * __uint_as_float(vv.w & 0xffff0000u);
    }

    uint4 ou;
    ou.x = (unsigned)f2bf(o[0] * inv) | ((unsigned)f2bf(o[1] * inv) << 16);
    ou.y = (unsigned)f2bf(o[2] * inv) | ((unsigned)f2bf(o[3] * inv) << 16);
    ou.z = (unsigned)f2bf(o[4] * inv) | ((unsigned)f2bf(o[5] * inv) << 16);
    ou.w = (unsigned)f2bf(o[6] * inv) | ((unsigned)f2bf(o[7] * inv) << 16);
    *(uint4*)(aout + ((size_t)b * SVOX + sv) * CIN + n * HDIM + sub * 8) = ou;
}

// ---------------------------------------------------------------------------
// Kernel 3: proj GEMM, 64(o) x 64(s), K=128 single shot, bf16 W preconv.
// ---------------------------------------------------------------------------
__global__ __launch_bounds__(256) void proj_gemm(
    const ushort* __restrict__ Xa,
    const ushort* __restrict__ Wg,
    const float* __restrict__ bias,
    float* __restrict__ out)
{
    __shared__ __align__(16) unsigned char smem[34816];
    ushort* Wb = (ushort*)smem;                 // [64][136] bf16
    ushort* Xs = (ushort*)(smem + 17408);       // [64 s][136 k] bf16
    float*  T  = (float*)smem;                  // epilogue alias [64][72]

    const int t    = threadIdx.x;
    const int s0   = blockIdx.x * 64;
    const int o0   = blockIdx.y * 64;
    const int b    = blockIdx.z;
    const int lane = t & 63;
    const int wid  = t >> 6;
    const int l15  = lane & 15;
    const int g4   = lane >> 4;
    const int wm   = (wid >> 1) * 32;
    const int wn   = (wid & 1) * 32;

    // stage W [64][128] bf16 (straight copy)
    #pragma unroll
    for (int i = 0; i < 4; i++) {
        int f = t + i * 256;
        int row = f >> 4, c8 = f & 15;
        *(uint4*)(Wb + row * 136 + c8 * 8) =
            *(const uint4*)(Wg + (size_t)(o0 + row) * CIN + c8 * 8);
    }
    // stage X [64 s][128 c] bf16 (straight copy)
    #pragma unroll
    for (int i = 0; i < 4; i++) {
        int f = t + i * 256;
        int row = f >> 4, c8 = f & 15;
        *(uint4*)(Xs + row * 136 + c8 * 8) =
            *(const uint4*)(Xa + ((size_t)b * SVOX + s0 + row) * CIN + c8 * 8);
    }
    __syncthreads();

    f32x4 acc[2][2];
    #pragma unroll
    for (int mf = 0; mf < 2; mf++)
        #pragma unroll
        for (int nf = 0; nf < 2; nf++)
            acc[mf][nf] = (f32x4){0.f, 0.f, 0.f, 0.f};

    #pragma unroll
    for (int ks = 0; ks < 4; ks++) {
        short8 Af[2], Bf[2];
        #pragma unroll
        for (int mf = 0; mf < 2; mf++)
            Af[mf] = *(const short8*)(Wb + (wm + mf * 16 + l15) * 136 + ks * 32 + g4 * 8);
        #pragma unroll
        for (int nf = 0; nf < 2; nf++)
            Bf[nf] = *(const short8*)(Xs + (wn + nf * 16 + l15) * 136 + ks * 32 + g4 * 8);
        #pragma unroll
        for (int mf = 0; mf < 2; mf++)
            #pragma unroll
            for (int nf = 0; nf < 2; nf++)
                acc[mf][nf] = __builtin_amdgcn_mfma_f32_16x16x32_bf16(Af[mf], Bf[nf], acc[mf][nf], 0, 0, 0);
    }

    __syncthreads();
    #pragma unroll
    for (int mf = 0; mf < 2; mf++)
        #pragma unroll
        for (int nf = 0; nf < 2; nf++) {
            int s  = wn + nf * 16 + l15;
            int mb = wm + mf * 16 + g4 * 4;
            #pragma unroll
            for (int r = 0; r < 4; r++)
                T[(mb + r) * 72 + s] = acc[mf][nf][r];
        }
    __syncthreads();
    #pragma unroll
    for (int i = 0; i < 4; i++) {
        int f = t + i * 256;
        int s4 = f & 15, m = f >> 4;
        float4 v = *(float4*)(T + m * 72 + s4 * 4);
        float bi = bias[o0 + m];
        v.x += bi; v.y += bi; v.z += bi; v.w += bi;
        *(float4*)(out + ((size_t)b * CIN + o0 + m) * SVOX + s0 + s4 * 4) = v;
    }
}

extern "C" void kernel_launch(void* const* d_in, const int* in_sizes, int n_in,
                              void* d_out, int out_size, void* d_ws, size_t ws_size,
                              hipStream_t stream) {
    const float* x      = (const float*)d_in[0];
    const float* qkv_w  = (const float*)d_in[1];
    const float* qkv_b  = (const float*)d_in[2];
    const float* proj_w = (const float*)d_in[3];
    const float* proj_b = (const float*)d_in[4];
    const float* pos    = (const float*)d_in[5];
    float* out = (float*)d_out;

    const size_t HSZ = (size_t)2 * NHEAD * SVOX * HDIM;   // elems per q/k/v tensor
    ushort* qb  = (ushort*)d_ws;                          // bf16 [2][4][S][32]
    ushort* kbp = qb + HSZ;
    ushort* vbp = kbp + HSZ;
    ushort* attn_o = vbp + HSZ;                           // bf16 [2][S][128]
    ushort* Wq  = attn_o + HSZ;                           // bf16 [384][128]
    ushort* Wp  = Wq + 384 * CIN;                         // bf16 [128][128]
    unsigned* pe_p = (unsigned*)(Wp + CIN * CIN);         // [27][16] packed pairs

    prep_kernel<<<34, 256, 0, stream>>>(qkv_w, proj_w, pos, Wq, Wp, pe_p);
    qkv_gemm<<<dim3(1296, 1, 2), 256, 0, stream>>>(x, Wq, qkv_b, qb, kbp, vbp);
    attn_kernel<<<dim3(216, NHEAD, 2), 256, 0, stream>>>(qb, kbp, vbp, pe_p, attn_o);
    proj_gemm<<<dim3(SVOX/64, CIN/64, 2), 256, 0, stream>>>(attn_o, Wp, proj_b, out);
}

// Round 11
// 46.323 us; speedup vs baseline: 1.0770x; 1.0635x over previous
//
#include <hip/hip_runtime.h>
#include <hip/hip_bf16.h>
#include <hip/hip_fp16.h>

#define SVOX 13824   // 24*24*24
#define CIN 128
#define NHEAD 4
#define HDIM 32

// attention brick geometry
#define BD 2
#define BH 4
#define BW 8
#define WD (BD+2)
#define WH (BH+2)
#define WW (BW+2)
#define NWIN (WD*WH*WW)   // 240

typedef __attribute__((ext_vector_type(8))) short short8;
typedef __attribute__((ext_vector_type(4))) float f32x4;
#if defined(__has_builtin)
#if __has_builtin(__builtin_amdgcn_fdot2_f32_bf16)
#define HAVE_DOT2BF 1
typedef __attribute__((ext_vector_type(2))) __bf16 bf16x2;
#endif
#if __has_builtin(__builtin_amdgcn_mov_dpp)
#define HAVE_DPP 1
#endif
#if __has_builtin(__builtin_amdgcn_cvt_pkrtz)
#define HAVE_PKRTZ 1
#endif
#endif

__device__ __forceinline__ unsigned short f2bf(float x) {
    unsigned u = __float_as_uint(x);
    u += 0x7FFFu + ((u >> 16) & 1u);
    return (unsigned short)(u >> 16);
}
__device__ __forceinline__ float dot2bf(unsigned a, unsigned b, float c) {
#ifdef HAVE_DOT2BF
    return __builtin_amdgcn_fdot2_f32_bf16(__builtin_bit_cast(bf16x2, a),
                                           __builtin_bit_cast(bf16x2, b), c, false);
#else
    return __uint_as_float(a << 16) * __uint_as_float(b << 16)
         + __uint_as_float(a & 0xffff0000u) * __uint_as_float(b & 0xffff0000u) + c;
#endif
}
template<int CTRL>
__device__ __forceinline__ float quad_dpp(float x) {
#ifdef HAVE_DPP
    return __int_as_float(__builtin_amdgcn_mov_dpp(__float_as_int(x), CTRL, 0xf, 0xf, true));
#else
    return __shfl_xor(x, (CTRL == 0xB1) ? 1 : 2);
#endif
}
__device__ __forceinline__ __half2 u2h2(unsigned u) {
    union { unsigned u; __half2 h; } c; c.u = u; return c.h;
}
__device__ __forceinline__ __half2 splat_h2(float x) {
#ifdef HAVE_PKRTZ
    auto v = __builtin_amdgcn_cvt_pkrtz(x, x);   // v_cvt_pkrtz_f16_f32, 1 instr
    union { decltype(v) a; __half2 h; } c; c.a = v; return c.h;
#else
    return __float2half2_rn(x);
#endif
}
__device__ __forceinline__ unsigned short f2h(float x) {
    return __builtin_bit_cast(unsigned short, (_Float16)x);
}

// ---------------------------------------------------------------------------
// Kernel 1: QKV GEMM, pure bf16 MFMA. Block(0,0,0) also packs the pos table.
// q,k stored bf16; v stored f16 (feeds packed-half PV in attention).
// ---------------------------------------------------------------------------
__global__ __launch_bounds__(256) void qkv_gemm(
    const float* __restrict__ X,
    const float* __restrict__ W,
    const float* __restrict__ bias,
    const float* __restrict__ pos,
    unsigned* __restrict__ pe_out,
    ushort* __restrict__ q_out,
    ushort* __restrict__ k_out,
    ushort* __restrict__ v_out)
{
    __shared__ __align__(16) unsigned char smem[26624];
    ushort* Wb = (ushort*)smem;                 // [64][136] bf16
    ushort* Xs = (ushort*)(smem + 17408);       // [64 s][72 k] bf16
    float*  T  = (float*)smem;                  // epilogue alias [64][68]

    const int t    = threadIdx.x;
    const int s0   = blockIdx.x * 64;
    const int o0   = blockIdx.y * 64;
    const int b    = blockIdx.z;
    const int lane = t & 63;
    const int wid  = t >> 6;
    const int l15  = lane & 15;
    const int g4   = lane >> 4;
    const int wm   = (wid >> 1) * 32;
    const int wn   = (wid & 1) * 32;

    if (blockIdx.x == 0 && blockIdx.y == 0 && blockIdx.z == 0 && t < 27 * 16) {
        int w = t >> 4, cp = t & 15;
        unsigned lo = f2bf(pos[(2 * cp) * 27 + w]);
        unsigned hi = f2bf(pos[(2 * cp + 1) * 27 + w]);
        pe_out[t] = lo | (hi << 16);
    }

    // stage W [64][128] as bf16
    #pragma unroll
    for (int i = 0; i < 8; i++) {
        int f = t + i * 256;
        int row = f >> 5, c4 = f & 31;
        float4 w = *(const float4*)(W + (size_t)(o0 + row) * CIN + c4 * 4);
        ushort4 u;
        u.x = f2bf(w.x); u.y = f2bf(w.y); u.z = f2bf(w.z); u.w = f2bf(w.w);
        *(ushort4*)(Wb + row * 136 + c4 * 4) = u;
    }

    f32x4 acc[2][2];
    #pragma unroll
    for (int mf = 0; mf < 2; mf++)
        #pragma unroll
        for (int nf = 0; nf < 2; nf++)
            acc[mf][nf] = (f32x4){0.f, 0.f, 0.f, 0.f};

    const int sx = t & 63;
    const int kg = t >> 6;

    for (int chunk = 0; chunk < 2; chunk++) {
        __syncthreads();
        ushort xk[16];
        #pragma unroll
        for (int i = 0; i < 16; i++) {
            int k = kg * 16 + i;
            xk[i] = f2bf(X[((size_t)b * CIN + chunk * 64 + k) * SVOX + s0 + sx]);
        }
        #pragma unroll
        for (int j = 0; j < 2; j++) {
            short8 v;
            #pragma unroll
            for (int e = 0; e < 8; e++) v[e] = (short)xk[j * 8 + e];
            *(short8*)(Xs + sx * 72 + kg * 16 + j * 8) = v;
        }
        __syncthreads();

        #pragma unroll
        for (int ks = 0; ks < 2; ks++) {
            short8 Af[2], Bf[2];
            #pragma unroll
            for (int mf = 0; mf < 2; mf++)
                Af[mf] = *(const short8*)(Wb + (wm + mf * 16 + l15) * 136 + chunk * 64 + ks * 32 + g4 * 8);
            #pragma unroll
            for (int nf = 0; nf < 2; nf++)
                Bf[nf] = *(const short8*)(Xs + (wn + nf * 16 + l15) * 72 + ks * 32 + g4 * 8);
            #pragma unroll
            for (int mf = 0; mf < 2; mf++)
                #pragma unroll
                for (int nf = 0; nf < 2; nf++)
                    acc[mf][nf] = __builtin_amdgcn_mfma_f32_16x16x32_bf16(Af[mf], Bf[nf], acc[mf][nf], 0, 0, 0);
        }
    }

    __syncthreads();
    #pragma unroll
    for (int mf = 0; mf < 2; mf++)
        #pragma unroll
        for (int nf = 0; nf < 2; nf++) {
            int s  = wn + nf * 16 + l15;
            int mb = wm + mf * 16 + g4 * 4;
            *(f32x4*)(T + s * 68 + mb) = acc[mf][nf];
        }
    __syncthreads();
    #pragma unroll
    for (int i = 0; i < 4; i++) {
        int f = t + i * 256;
        int og = f & 15, sl = f >> 4;
        float4 v = *(float4*)(T + sl * 68 + og * 4);
        int o_g = o0 + og * 4;
        v.x += bias[o_g]; v.y += bias[o_g + 1]; v.z += bias[o_g + 2]; v.w += bias[o_g + 3];
        int part = o_g >> 7, pc = o_g & 127;
        int head = pc >> 5, ic = pc & 31;
        size_t base = (((size_t)b * NHEAD + head) * SVOX + s0 + sl) * HDIM + ic;
        ushort4 u;
        if (part == 2) {      // V -> f16 (for packed-half PV)
            u.x = f2h(v.x); u.y = f2h(v.y); u.z = f2h(v.z); u.w = f2h(v.w);
        } else {              // Q,K -> bf16 (for dot2bf)
            u.x = f2bf(v.x); u.y = f2bf(v.y); u.z = f2bf(v.z); u.w = f2bf(v.w);
        }
        ushort* dst = (part == 0) ? q_out : (part == 1) ? k_out : v_out;
        *(ushort4*)(dst + base) = u;
    }
}

// ---------------------------------------------------------------------------
// Kernel 2: brick-LDS windowed attention. V in f16, PV via v_pk_fma_f16;
// softmax max via max3 triples; scale*log2e folded into exp2f.
// ---------------------------------------------------------------------------
__global__ __launch_bounds__(256, 5) void attn_kernel(
    const ushort* __restrict__ qbf,
    const ushort* __restrict__ kbf,
    const ushort* __restrict__ vhf,
    const unsigned* __restrict__ pe_g,
    ushort* __restrict__ aout)
{
    __shared__ __align__(16) ushort Kl[NWIN * 32];       // 15360 B (bf16)
    __shared__ __align__(16) ushort Vl[NWIN * 32];       // 15360 B (f16)

    const int t = threadIdx.x;
    const int br = blockIdx.x;           // 216 bricks: 12(d) x 6(h) x 3(w)
    const int n  = blockIdx.y;
    const int b  = blockIdx.z;
    const int bw_ = br % 3;
    const int bh_ = (br / 3) % 6;
    const int bd_ = br / 18;
    const int d0 = bd_ * BD, h0 = bh_ * BH, w0 = bw_ * BW;

    const ushort* kb = kbf + ((size_t)b * NHEAD + n) * (size_t)SVOX * HDIM;
    const ushort* vb = vhf + ((size_t)b * NHEAD + n) * (size_t)SVOX * HDIM;

    #pragma unroll
    for (int i = 0; i < 4; i++) {
        int f = t + i * 256;
        if (f < NWIN * 4) {
            int u = f >> 2, ch = f & 3;
            int ud = u / (WH * WW);
            int r  = u - ud * (WH * WW);
            int uh = r / WW;
            int uw = r - uh * WW;
            int gd = d0 + ud - 1, gh = h0 + uh - 1, gw = w0 + uw - 1;
            bool valid = ((unsigned)gd < 24u) & ((unsigned)gh < 24u) & ((unsigned)gw < 24u);
            size_t gsv = valid ? (size_t)(gd * 576 + gh * 24 + gw) : 0;
            uint4 kv = *(const uint4*)(kb + gsv * HDIM + ch * 8);
            uint4 vv = *(const uint4*)(vb + gsv * HDIM + ch * 8);
            if (!valid) { kv = make_uint4(0,0,0,0); vv = make_uint4(0,0,0,0); }
            *(uint4*)(Kl + u * 32 + ch * 8) = kv;
            *(uint4*)(Vl + u * 32 + ch * 8) = vv;
        }
    }

    const int p   = t >> 2;          // local voxel 0..63
    const int sub = t & 3;           // 8-channel group
    const int pw = p & 7, ph = (p >> 3) & 3, pd = p >> 5;
    const int sv = (d0 + pd) * 576 + (h0 + ph) * 24 + w0 + pw;
    uint4 qpk = *(const uint4*)(qbf + (((size_t)b * NHEAD + n) * SVOX + sv) * HDIM + sub * 8);

    // q . pos partials from global pe table (L1 broadcast), overlaps staging
    float sc[27];
    #pragma unroll
    for (int s = 0; s < 27; s++) {
        uint4 pp = *(const uint4*)(pe_g + s * 16 + sub * 4);
        float a = dot2bf(qpk.x, pp.x, 0.f);
        a = dot2bf(qpk.y, pp.y, a);
        a = dot2bf(qpk.z, pp.z, a);
        a = dot2bf(qpk.w, pp.w, a);
        sc[s] = a;
    }

    __syncthreads();

    const int wc = (pd + 1) * (WH * WW) + (ph + 1) * WW + (pw + 1);
    const ushort* Kbase = Kl + wc * 32 + sub * 8;

    #pragma unroll
    for (int s = 0; s < 27; s++) {
        const int di = s / 9 - 1, dj = (s / 3) % 3 - 1, dl = s % 3 - 1;
        const int off = (di * (WH * WW) + dj * WW + dl) * 32;
        uint4 kk = *(const uint4*)(Kbase + off);
        float a = sc[s];
        a = dot2bf(qpk.x, kk.x, a);
        a = dot2bf(qpk.y, kk.y, a);
        a = dot2bf(qpk.z, kk.z, a);
        a = dot2bf(qpk.w, kk.w, a);
        sc[s] = a;
    }

    #pragma unroll
    for (int s = 0; s < 27; s++) {
        sc[s] += quad_dpp<0xB1>(sc[s]);   // xor 1
        sc[s] += quad_dpp<0x4E>(sc[s]);   // xor 2
    }

    // max over raw scores via max3 triples (scale > 0 preserves order)
    float m3[9];
    #pragma unroll
    for (int j = 0; j < 9; j++)
        m3[j] = fmaxf(fmaxf(sc[3*j], sc[3*j+1]), sc[3*j+2]);
    float m9a = fmaxf(fmaxf(m3[0], m3[1]), m3[2]);
    float m9b = fmaxf(fmaxf(m3[3], m3[4]), m3[5]);
    float m9c = fmaxf(fmaxf(m3[6], m3[7]), m3[8]);
    float mx  = fmaxf(fmaxf(m9a, m9b), m9c);

    // exp(scale*(sc-mx)) = exp2(KS*(sc-mx)), KS = scale*log2(e)
    const float KS = 0.17677669529663687f * 1.4426950408889634f;
    float sum = 0.f;
    #pragma unroll
    for (int s = 0; s < 27; s++) {
        float e = exp2f((sc[s] - mx) * KS);
        sc[s] = e;
        sum += e;
    }
    float inv = 1.f / sum;

    // PV: f16 V via packed-half fma (v_pk_fma_f16)
    const ushort* Vbase = Vl + wc * 32 + sub * 8;
    __half2 o2[4];
    __half2 hz = __float2half2_rn(0.f);
    o2[0] = hz; o2[1] = hz; o2[2] = hz; o2[3] = hz;
    #pragma unroll
    for (int s = 0; s < 27; s++) {
        const int di = s / 9 - 1, dj = (s / 3) % 3 - 1, dl = s % 3 - 1;
        const int off = (di * (WH * WW) + dj * WW + dl) * 32;
        uint4 vv = *(const uint4*)(Vbase + off);
        __half2 p2 = splat_h2(sc[s]);
        o2[0] = __hfma2(p2, u2h2(vv.x), o2[0]);
        o2[1] = __hfma2(p2, u2h2(vv.y), o2[1]);
        o2[2] = __hfma2(p2, u2h2(vv.z), o2[2]);
        o2[3] = __hfma2(p2, u2h2(vv.w), o2[3]);
    }

    float o[8];
    #pragma unroll
    for (int j = 0; j < 4; j++) {
        o[2*j]   = __low2float(o2[j]);
        o[2*j+1] = __high2float(o2[j]);
    }

    uint4 ou;
    ou.x = (unsigned)f2bf(o[0] * inv) | ((unsigned)f2bf(o[1] * inv) << 16);
    ou.y = (unsigned)f2bf(o[2] * inv) | ((unsigned)f2bf(o[3] * inv) << 16);
    ou.z = (unsigned)f2bf(o[4] * inv) | ((unsigned)f2bf(o[5] * inv) << 16);
    ou.w = (unsigned)f2bf(o[6] * inv) | ((unsigned)f2bf(o[7] * inv) << 16);
    *(uint4*)(aout + ((size_t)b * SVOX + sv) * CIN + n * HDIM + sub * 8) = ou;
}

// ---------------------------------------------------------------------------
// Kernel 3: proj GEMM, pure bf16 MFMA (R8 version).
// ---------------------------------------------------------------------------
__global__ __launch_bounds__(256) void proj_gemm(
    const ushort* __restrict__ Xa,
    const float* __restrict__ W,
    const float* __restrict__ bias,
    float* __restrict__ out)
{
    __shared__ __align__(16) unsigned char smem[34816];
    ushort* Wb = (ushort*)smem;                 // [64][136] bf16
    ushort* Xs = (ushort*)(smem + 17408);       // [64 s][136 k] bf16
    float*  T  = (float*)smem;                  // epilogue alias [64][72]

    const int t    = threadIdx.x;
    const int s0   = blockIdx.x * 64;
    const int o0   = blockIdx.y * 64;
    const int b    = blockIdx.z;
    const int lane = t & 63;
    const int wid  = t >> 6;
    const int l15  = lane & 15;
    const int g4   = lane >> 4;
    const int wm   = (wid >> 1) * 32;
    const int wn   = (wid & 1) * 32;

    #pragma unroll
    for (int i = 0; i < 8; i++) {
        int f = t + i * 256;
        int row = f >> 5, c4 = f & 31;
        float4 w = *(const float4*)(W + (size_t)(o0 + row) * CIN + c4 * 4);
        ushort4 u;
        u.x = f2bf(w.x); u.y = f2bf(w.y); u.z = f2bf(w.z); u.w = f2bf(w.w);
        *(ushort4*)(Wb + row * 136 + c4 * 4) = u;
    }
    #pragma unroll
    for (int i = 0; i < 4; i++) {
        int f = t + i * 256;
        int row = f >> 4, c8 = f & 15;
        *(uint4*)(Xs + row * 136 + c8 * 8) =
            *(const uint4*)(Xa + ((size_t)b * SVOX + s0 + row) * CIN + c8 * 8);
    }
    __syncthreads();

    f32x4 acc[2][2];
    #pragma unroll
    for (int mf = 0; mf < 2; mf++)
        #pragma unroll
        for (int nf = 0; nf < 2; nf++)
            acc[mf][nf] = (f32x4){0.f, 0.f, 0.f, 0.f};

    #pragma unroll
    for (int ks = 0; ks < 4; ks++) {
        short8 Af[2], Bf[2];
        #pragma unroll
        for (int mf = 0; mf < 2; mf++)
            Af[mf] = *(const short8*)(Wb + (wm + mf * 16 + l15) * 136 + ks * 32 + g4 * 8);
        #pragma unroll
        for (int nf = 0; nf < 2; nf++)
            Bf[nf] = *(const short8*)(Xs + (wn + nf * 16 + l15) * 136 + ks * 32 + g4 * 8);
        #pragma unroll
        for (int mf = 0; mf < 2; mf++)
            #pragma unroll
            for (int nf = 0; nf < 2; nf++)
                acc[mf][nf] = __builtin_amdgcn_mfma_f32_16x16x32_bf16(Af[mf], Bf[nf], acc[mf][nf], 0, 0, 0);
    }

    __syncthreads();
    #pragma unroll
    for (int mf = 0; mf < 2; mf++)
        #pragma unroll
        for (int nf = 0; nf < 2; nf++) {
            int s  = wn + nf * 16 + l15;
            int mb = wm + mf * 16 + g4 * 4;
            #pragma unroll
            for (int r = 0; r < 4; r++)
                T[(mb + r) * 72 + s] = acc[mf][nf][r];
        }
    __syncthreads();
    #pragma unroll
    for (int i = 0; i < 4; i++) {
        int f = t + i * 256;
        int s4 = f & 15, m = f >> 4;
        float4 v = *(float4*)(T + m * 72 + s4 * 4);
        float bi = bias[o0 + m];
        v.x += bi; v.y += bi; v.z += bi; v.w += bi;
        *(float4*)(out + ((size_t)b * CIN + o0 + m) * SVOX + s0 + s4 * 4) = v;
    }
}

extern "C" void kernel_launch(void* const* d_in, const int* in_sizes, int n_in,
                              void* d_out, int out_size, void* d_ws, size_t ws_size,
                              hipStream_t stream) {
    const float* x      = (const float*)d_in[0];
    const float* qkv_w  = (const float*)d_in[1];
    const float* qkv_b  = (const float*)d_in[2];
    const float* proj_w = (const float*)d_in[3];
    const float* proj_b = (const float*)d_in[4];
    const float* pos    = (const float*)d_in[5];
    float* out = (float*)d_out;

    const size_t HSZ = (size_t)2 * NHEAD * SVOX * HDIM;   // elems per q/k/v tensor
    ushort* qb  = (ushort*)d_ws;                          // bf16 [2][4][S][32]
    ushort* kbp = qb + HSZ;                               // bf16
    ushort* vbp = kbp + HSZ;                              // f16
    ushort* attn_o = vbp + HSZ;                           // bf16 [2][S][128]
    unsigned* pe_p = (unsigned*)(attn_o + HSZ);           // [27][16] packed bf16 pairs

    qkv_gemm<<<dim3(SVOX/64, 384/64, 2), 256, 0, stream>>>(x, qkv_w, qkv_b, pos, pe_p, qb, kbp, vbp);
    attn_kernel<<<dim3(216, NHEAD, 2), 256, 0, stream>>>(qb, kbp, vbp, pe_p, attn_o);
    proj_gemm<<<dim3(SVOX/64, CIN/64, 2), 256, 0, stream>>>(attn_o, proj_w, proj_b, out);
}